// Round 1
// baseline (2214.901 us; speedup 1.0000x reference)
//
#include <hip/hip_runtime.h>

#define B_TOT 65536
#define T_LEN 34
#define HD 64

__device__ __forceinline__ float fsigmoid(float x){ return 1.0f/(1.0f+__expf(-x)); }
__device__ __forceinline__ float ftanh_(float x){ return 1.0f - 2.0f/(__expf(2.0f*x)+1.0f); }
__device__ __forceinline__ float felu(float x){ return x>0.0f ? x : (__expf(x)-1.0f); }

// ---------------- Kernel A: forward-fill + GRU + attention pooling ----------------
// 256 threads = 4 waves; each wave processes 4 rows concurrently. 16 rows/block.
__global__ __launch_bounds__(256)
void gru_attn_kernel(const float* __restrict__ Xin, const float* __restrict__ FA,
                     const float* __restrict__ Wih, const float* __restrict__ Whh,
                     const float* __restrict__ bih, const float* __restrict__ bhh,
                     const float* __restrict__ swT, const float* __restrict__ swM,
                     float* __restrict__ hT_out, float* __restrict__ hM_out)
{
    __shared__ float4 Wp[64][64];          // [j][i] = (Wr[i][j], Wz[i][j], Wn[i][j], 0) -> ds_read_b128 conflict-free
    __shared__ float  sh [4][4][HD];       // [wave][rr][j] hidden state (broadcast reads)
    __shared__ float  sxf[4][4][T_LEN];
    __shared__ float  sff[4][4][T_LEN];

    const int tid  = threadIdx.x;
    const int lane = tid & 63;
    const int wv   = tid >> 6;

    // stage Whh -> Wp (once per block)
    for (int it = 0; it < 16; ++it) {
        int j = wv + it*4;
        float a = Whh[(      lane)*64 + j];
        float b = Whh[( 64 + lane)*64 + j];
        float c = Whh[(128 + lane)*64 + j];
        Wp[j][lane] = make_float4(a, b, c, 0.0f);
    }

    const int rowbase = blockIdx.x*16 + wv*4;

    // forward-fill (segmented LOCF) via prefix-max over lanes; lane t handles time t
    #pragma unroll
    for (int rr = 0; rr < 4; ++rr) {
        int row = rowbase + rr;
        float X = 0.0f, fa = 0.0f; int idx = -1;
        if (lane < T_LEN) {
            X  = Xin[row*T_LEN + lane];
            fa = FA [row*T_LEN + lane];
            if (X != 0.0f) idx = lane;
        }
        #pragma unroll
        for (int off = 1; off < 64; off <<= 1) {
            int v = __shfl_up(idx, off);
            if (lane >= off && v > idx) idx = v;
        }
        int gsrc = idx < 0 ? 0 : idx;
        float Xg = __shfl(X,  gsrc);
        float fg = __shfl(fa, gsrc);
        if (idx < 0) { Xg = 0.0f; fg = 0.0f; }
        if (lane < T_LEN) { sxf[wv][rr][lane] = Xg; sff[wv][rr][lane] = fg; }
        sh[wv][rr][lane] = 0.0f;
    }
    __syncthreads();

    // per-lane (per hidden unit) weights
    const float wrx = Wih[ lane     *2+0], wrf = Wih[ lane     *2+1];
    const float wzx = Wih[( 64+lane)*2+0], wzf = Wih[( 64+lane)*2+1];
    const float wnx = Wih[(128+lane)*2+0], wnf = Wih[(128+lane)*2+1];
    const float br  = bih[lane], bz  = bih[64+lane], bn  = bih[128+lane];
    const float brh = bhh[lane], bzh = bhh[64+lane], bnh = bhh[128+lane];
    const float wT  = swT[lane], wM  = swM[lane];

    float h[4]    = {0,0,0,0};
    float numT[4] = {0,0,0,0}, numM[4] = {0,0,0,0};
    float denT[4] = {0,0,0,0}, denM[4] = {0,0,0,0};

    for (int t = 0; t < T_LEN; ++t) {
        float Sr[4], Sz[4], Sn[4];
        #pragma unroll
        for (int rr = 0; rr < 4; ++rr) { Sr[rr]=brh; Sz[rr]=bzh; Sn[rr]=bnh; }
        #pragma unroll 4
        for (int j = 0; j < 64; ++j) {
            float4 w = Wp[j][lane];
            #pragma unroll
            for (int rr = 0; rr < 4; ++rr) {
                float hj = sh[wv][rr][j];
                Sr[rr] = fmaf(w.x, hj, Sr[rr]);
                Sz[rr] = fmaf(w.y, hj, Sz[rr]);
                Sn[rr] = fmaf(w.z, hj, Sn[rr]);
            }
        }
        #pragma unroll
        for (int rr = 0; rr < 4; ++rr) {
            float xq = sxf[wv][rr][t], fq = sff[wv][rr][t];
            float r = fsigmoid(fmaf(wrx,xq,fmaf(wrf,fq,br)) + Sr[rr]);
            float z = fsigmoid(fmaf(wzx,xq,fmaf(wzf,fq,bz)) + Sz[rr]);
            float n = ftanh_ (fmaf(wnx,xq,fmaf(wnf,fq,bn)) + r*Sn[rr]);
            float hn = (1.0f - z)*n + z*h[rr];
            h[rr] = hn;
            sh[wv][rr][lane] = hn;
            // online attention pooling (softmax over T, no mask in reference)
            float vT = hn*wT, vM = hn*wM;
            #pragma unroll
            for (int off = 1; off < 64; off <<= 1) {
                vT += __shfl_xor(vT, off);
                vM += __shfl_xor(vM, off);
            }
            float eT = __expf(vT), eM = __expf(vM);
            denT[rr] += eT;                 denM[rr] += eM;
            numT[rr] = fmaf(eT, hn, numT[rr]); numM[rr] = fmaf(eM, hn, numM[rr]);
        }
    }
    #pragma unroll
    for (int rr = 0; rr < 4; ++rr) {
        int row = rowbase + rr;
        hT_out[row*HD + lane] = numT[rr]/denT[rr];
        hM_out[row*HD + lane] = numM[rr]/denM[rr];
    }
}

// ---------------- Kernel B: both MLP heads + T10/M0 + X_out ----------------
// 256 threads, 32 rows/block. Thread = (r = tid&31, g = tid>>5); each thread owns
// 25 neurons (n = g + 8*i). Layer2 output feeds layer3 dot on the fly (no storage).
__global__ __launch_bounds__(256)
void mlp_out_kernel(const float* __restrict__ hT, const float* __restrict__ hM,
    const float* __restrict__ TW1, const float* __restrict__ Tb1,
    const float* __restrict__ TW2, const float* __restrict__ Tb2,
    const float* __restrict__ TW3, const float* __restrict__ Tb3,
    const float* __restrict__ MW1, const float* __restrict__ Mb1,
    const float* __restrict__ MW2, const float* __restrict__ Mb2,
    const float* __restrict__ MW3, const float* __restrict__ Mb3,
    const float* __restrict__ FA, const float* __restrict__ TR,
    float* __restrict__ out)
{
    __shared__ __align__(16) float xt[2][32][68];   // stride 68: 16B-aligned rows
    __shared__ __align__(16) float h1[32][204];     // stride 204: 16B-aligned rows
    __shared__ float part[8][32];
    __shared__ float rawv[2][32];
    __shared__ float Es[32], M0s[32];

    const int tid  = threadIdx.x;
    const int r    = tid & 31;
    const int g    = tid >> 5;
    const int row0 = blockIdx.x*32;

    for (int i = tid; i < 32*64; i += 256) {
        int rr = i >> 6, cc = i & 63;
        xt[0][rr][cc] = hT[(row0+rr)*64 + cc];
        xt[1][rr][cc] = hM[(row0+rr)*64 + cc];
    }
    __syncthreads();

    for (int brn = 0; brn < 2; ++brn) {
        const float* W1 = brn ? MW1 : TW1; const float* b1 = brn ? Mb1 : Tb1;
        const float* W2 = brn ? MW2 : TW2; const float* b2 = brn ? Mb2 : Tb2;
        const float* W3 = brn ? MW3 : TW3; const float* b3 = brn ? Mb3 : Tb3;

        // layer 1: [32,64] x [64,200]^T -> ELU -> h1
        #pragma unroll
        for (int jt = 0; jt < 5; ++jt) {
            float acc[5];
            int n0 = g + 40*jt;
            #pragma unroll
            for (int c = 0; c < 5; ++c) acc[c] = b1[n0 + 8*c];
            for (int k = 0; k < 64; k += 4) {
                float4 xv = *reinterpret_cast<const float4*>(&xt[brn][r][k]);
                #pragma unroll
                for (int c = 0; c < 5; ++c) {
                    float4 wv = *reinterpret_cast<const float4*>(&W1[(n0+8*c)*64 + k]);
                    acc[c] = fmaf(xv.x, wv.x, acc[c]);
                    acc[c] = fmaf(xv.y, wv.y, acc[c]);
                    acc[c] = fmaf(xv.z, wv.z, acc[c]);
                    acc[c] = fmaf(xv.w, wv.w, acc[c]);
                }
            }
            #pragma unroll
            for (int c = 0; c < 5; ++c) h1[r][n0 + 8*c] = felu(acc[c]);
        }
        __syncthreads();

        // layer 2 (ELU) fused with layer 3 dot
        float contrib = 0.0f;
        #pragma unroll
        for (int jt = 0; jt < 5; ++jt) {
            float acc[5];
            int n0 = g + 40*jt;
            #pragma unroll
            for (int c = 0; c < 5; ++c) acc[c] = b2[n0 + 8*c];
            for (int k = 0; k < 200; k += 4) {
                float4 xv = *reinterpret_cast<const float4*>(&h1[r][k]);
                #pragma unroll
                for (int c = 0; c < 5; ++c) {
                    float4 wv = *reinterpret_cast<const float4*>(&W2[(n0+8*c)*200 + k]);
                    acc[c] = fmaf(xv.x, wv.x, acc[c]);
                    acc[c] = fmaf(xv.y, wv.y, acc[c]);
                    acc[c] = fmaf(xv.z, wv.z, acc[c]);
                    acc[c] = fmaf(xv.w, wv.w, acc[c]);
                }
            }
            #pragma unroll
            for (int c = 0; c < 5; ++c)
                contrib = fmaf(W3[n0 + 8*c], felu(acc[c]), contrib);
        }
        part[g][r] = contrib;
        __syncthreads();
        if (tid < 32) {
            float s = b3[0];
            #pragma unroll
            for (int q = 0; q < 8; ++q) s += part[q][tid];
            rawv[brn][tid] = s;
        }
        __syncthreads();
    }

    if (tid < 32) {
        int row = row0 + tid;
        float T10 = 0.1f + 4.9f*fsigmoid(rawv[0][tid]);
        float M0  = 10000.0f*fsigmoid(rawv[1][tid]);
        Es[tid]  = __expf(-TR[row]/T10);
        M0s[tid] = M0;
        out[(size_t)B_TOT*T_LEN + row]         = T10;
        out[(size_t)B_TOT*T_LEN + B_TOT + row] = M0;
    }
    __syncthreads();

    for (int i = tid; i < 32*T_LEN; i += 256) {
        int rr = i / T_LEN, t = i - rr*T_LEN;
        int row = row0 + rr;
        float fa = FA[row*T_LEN + t];
        float s = __sinf(fa), c = __cosf(fa);
        float Ev = Es[rr];
        out[row*T_LEN + t] = (1.0f - Ev)*s/(1.0f - c*Ev)*M0s[rr];
    }
}

extern "C" void kernel_launch(void* const* d_in, const int* in_sizes, int n_in,
                              void* d_out, int out_size, void* d_ws, size_t ws_size,
                              hipStream_t stream) {
    const float* Xin = (const float*)d_in[0];   // X_fa_in  [B,T]
    const float* FA  = (const float*)d_in[1];   // fa_vals  [B,T]
    // d_in[2] fa_mask, d_in[3] fa_len: unused
    const float* TR  = (const float*)d_in[4];   // TR_vals  [B,1]
    const float* Wih = (const float*)d_in[5];
    const float* Whh = (const float*)d_in[6];
    const float* bih = (const float*)d_in[7];
    const float* bhh = (const float*)d_in[8];
    const float* swT = (const float*)d_in[9];
    const float* swM = (const float*)d_in[10];
    const float* TW1 = (const float*)d_in[11]; const float* Tb1 = (const float*)d_in[12];
    const float* TW2 = (const float*)d_in[13]; const float* Tb2 = (const float*)d_in[14];
    const float* TW3 = (const float*)d_in[15]; const float* Tb3 = (const float*)d_in[16];
    const float* MW1 = (const float*)d_in[17]; const float* Mb1 = (const float*)d_in[18];
    const float* MW2 = (const float*)d_in[19]; const float* Mb2 = (const float*)d_in[20];
    const float* MW3 = (const float*)d_in[21]; const float* Mb3 = (const float*)d_in[22];
    float* out = (float*)d_out;

    float* hT = (float*)d_ws;                       // [B,64]
    float* hM = hT + (size_t)B_TOT*HD;              // [B,64]  (total 33.6 MB of d_ws)

    gru_attn_kernel<<<B_TOT/16, 256, 0, stream>>>(Xin, FA, Wih, Whh, bih, bhh,
                                                  swT, swM, hT, hM);
    mlp_out_kernel<<<B_TOT/32, 256, 0, stream>>>(hT, hM,
                                                 TW1, Tb1, TW2, Tb2, TW3, Tb3,
                                                 MW1, Mb1, MW2, Mb2, MW3, Mb3,
                                                 FA, TR, out);
}

// Round 2
// 1318.396 us; speedup vs baseline: 1.6800x; 1.6800x over previous
//
#include <hip/hip_runtime.h>

#define B_TOT 65536
#define T_LEN 34
#define HD 64

typedef __attribute__((ext_vector_type(8))) short short8b;
typedef __attribute__((ext_vector_type(4))) float f32x4;

__device__ __forceinline__ float fsigmoid(float x){ return 1.0f/(1.0f+__expf(-x)); }
__device__ __forceinline__ float felu(float x){ return x>0.0f ? x : (__expf(x)-1.0f); }

// f32 -> bf16 round-to-nearest-even (for weights)
__device__ __forceinline__ unsigned short f2bf_rne(float f){
    unsigned int u = __float_as_uint(f);
    u += 0x7FFFu + ((u >> 16) & 1u);
    return (unsigned short)(u >> 16);
}
// f32 -> bf16 round-half-up (cheap, for per-step h)
__device__ __forceinline__ unsigned short f2bf_fast(float f){
    unsigned int u = __float_as_uint(f);
    return (unsigned short)((u + 0x8000u) >> 16);
}

// ---------------- Kernel A: forward-fill + GRU (MFMA) + attention pooling ----------------
// 4 waves/block, 16 rows/wave (64 rows/block). Whh as bf16 B-fragments in LDS,
// bias folded into MFMA C-init. h tile per wave in LDS (bf16, XOR-swizzled),
// h recurrence carried in f32 registers. Gates are lane-local after MFMA.
__global__ __launch_bounds__(256)
void gru_attn_mfma(const float* __restrict__ Xin, const float* __restrict__ FA,
                   const float* __restrict__ Wih, const float* __restrict__ Whh,
                   const float* __restrict__ bih, const float* __restrict__ bhh,
                   const float* __restrict__ swT, const float* __restrict__ swM,
                   float* __restrict__ hT_out, float* __restrict__ hM_out)
{
    __shared__ __align__(16) unsigned short WF[24*512];   // [ks*12+nt][lane][8] B-fragments, 24 KB
    __shared__ __align__(16) unsigned short HL[4][1024];  // per-wave h tile bf16 [16 rows][64 units], swizzled, 8 KB
    __shared__ __align__(8)  float XF[4][16][T_LEN][2];   // (x, fa) per wave,row,t  17 KB

    const int tid  = threadIdx.x;
    const int lane = tid & 63;
    const int wv   = tid >> 6;
    const int l16  = lane & 15;
    const int lhi  = lane >> 4;     // 0..3

    // ---- pack Whh -> B-fragments (frag f: k = ks*32 + lhi*8 + j, n = nt*16 + l16; B[k][n] = Whh[n][k]) ----
    for (int f = wv; f < 24; f += 4) {
        int ks = f / 12, nt = f % 12;
        int u  = nt*16 + l16;                 // unit 0..191
        int k0 = ks*32 + lhi*8;
        const float4 w0 = *reinterpret_cast<const float4*>(&Whh[u*64 + k0]);
        const float4 w1 = *reinterpret_cast<const float4*>(&Whh[u*64 + k0 + 4]);
        unsigned short* dst = &WF[f*512 + lane*8];
        dst[0]=f2bf_rne(w0.x); dst[1]=f2bf_rne(w0.y); dst[2]=f2bf_rne(w0.z); dst[3]=f2bf_rne(w0.w);
        dst[4]=f2bf_rne(w1.x); dst[5]=f2bf_rne(w1.y); dst[6]=f2bf_rne(w1.z); dst[7]=f2bf_rne(w1.w);
    }

    // zero h tile (t=0 reads zeros)
    #pragma unroll
    for (int i = 0; i < 16; ++i) HL[wv][i*64 + lane] = 0;

    const int rowbase = blockIdx.x*64 + wv*16;

    // ---- forward fill (segmented LOCF) via lane prefix-max; lane = time ----
    for (int rr = 0; rr < 16; ++rr) {
        int row = rowbase + rr;
        float X = 0.0f, fa = 0.0f; int idx = -1;
        if (lane < T_LEN) {
            X  = Xin[row*T_LEN + lane];
            fa = FA [row*T_LEN + lane];
            if (X != 0.0f) idx = lane;
        }
        #pragma unroll
        for (int off = 1; off < 64; off <<= 1) {
            int v = __shfl_up(idx, off);
            if (lane >= off && v > idx) idx = v;
        }
        int gsrc = idx < 0 ? 0 : idx;
        float Xg = __shfl(X,  gsrc);
        float fg = __shfl(fa, gsrc);
        if (idx < 0) { Xg = 0.0f; fg = 0.0f; }
        if (lane < T_LEN) { XF[wv][rr][lane][0] = Xg; XF[wv][rr][lane][1] = fg; }
    }

    // ---- per-lane constants ----
    float wrx[4], wrf[4], wzx[4], wzf[4], wnx[4], wnf[4], bihn[4], wTc[4], wMc[4], biasD[12];
    #pragma unroll
    for (int nt = 0; nt < 4; ++nt) {
        int ul = nt*16 + l16;                 // local unit 0..63
        wrx[nt] = Wih[ ul*2     ]; wrf[nt] = Wih[ ul*2     +1];
        wzx[nt] = Wih[(64+ul)*2 ]; wzf[nt] = Wih[(64+ul)*2 +1];
        wnx[nt] = Wih[(128+ul)*2]; wnf[nt] = Wih[(128+ul)*2+1];
        bihn[nt] = bih[128+ul];
        wTc[nt] = swT[ul]; wMc[nt] = swM[ul];
    }
    #pragma unroll
    for (int nt = 0; nt < 12; ++nt) {
        int u = nt*16 + l16;
        biasD[nt] = (nt < 8) ? (bih[u] + bhh[u]) : bhh[u];   // bhh_n is inside r*(.) per PyTorch GRU
    }

    __syncthreads();   // WF visible to all waves

    // A-fragment read addresses (row = l16, k = ks*32 + lhi*8 + j), XOR-swizzled granules
    const int swz   = (l16 & 7) << 3;
    const int aoff0 = l16*64 + ((     lhi*8) ^ swz);
    const int aoff1 = l16*64 + ((32 + lhi*8) ^ swz);

    float hreg[4][4] = {};                    // [q][nt], f32 recurrence state
    float numT[4][4] = {}, numM[4][4] = {};
    float denT[4]    = {}, denM[4]    = {};

    const unsigned short* HLr = HL[wv];
    unsigned short*       HLw = HL[wv];

    for (int t = 0; t < T_LEN; ++t) {
        short8b a0 = *reinterpret_cast<const short8b*>(&HLr[aoff0]);
        short8b a1 = *reinterpret_cast<const short8b*>(&HLr[aoff1]);
        f32x4 acc[12];
        #pragma unroll
        for (int nt = 0; nt < 12; ++nt) {
            float b = biasD[nt];
            acc[nt] = (f32x4){b, b, b, b};
            acc[nt] = __builtin_amdgcn_mfma_f32_16x16x32_bf16(
                a0, *reinterpret_cast<const short8b*>(&WF[ nt     *512 + lane*8]), acc[nt], 0, 0, 0);
            acc[nt] = __builtin_amdgcn_mfma_f32_16x16x32_bf16(
                a1, *reinterpret_cast<const short8b*>(&WF[(12+nt)*512 + lane*8]), acc[nt], 0, 0, 0);
        }
        // gates: element (q,nt) -> row = lhi*4+q, unit = nt*16+l16 (lane-local r/z/n)
        float vT[4], vM[4];
        #pragma unroll
        for (int q = 0; q < 4; ++q) {
            const int rloc = lhi*4 + q;
            const int rs   = (rloc & 7) << 3;
            float2 xf = *reinterpret_cast<const float2*>(&XF[wv][rloc][t][0]);
            float x = xf.x, fv = xf.y;
            float sT = 0.0f, sM = 0.0f;
            #pragma unroll
            for (int nt = 0; nt < 4; ++nt) {
                float Sr = acc[nt][q], Sz = acc[nt+4][q], Sn = acc[nt+8][q];
                float ur = fmaf(wrx[nt], x, fmaf(wrf[nt], fv, Sr));
                float uz = fmaf(wzx[nt], x, fmaf(wzf[nt], fv, Sz));
                float r  = 1.0f/(1.0f + __expf(-ur));
                float z  = 1.0f/(1.0f + __expf(-uz));
                float xn = fmaf(wnx[nt], x, fmaf(wnf[nt], fv, bihn[nt]));
                float v  = fmaf(r, Sn, xn);
                float n  = 1.0f - 2.0f/(1.0f + __expf(v + v));   // tanh(v)
                float hn = fmaf(z, hreg[q][nt] - n, n);
                hreg[q][nt] = hn;
                HLw[rloc*64 + ((((nt<<4) + l16)) ^ rs)] = f2bf_fast(hn);
                sT = fmaf(hn, wTc[nt], sT);
                sM = fmaf(hn, wMc[nt], sM);
            }
            vT[q] = sT; vM[q] = sM;
        }
        // online softmax pooling: reduce scores over the 16-lane row-group
        #pragma unroll
        for (int q = 0; q < 4; ++q) {
            float sT = vT[q], sM = vM[q];
            #pragma unroll
            for (int off = 1; off < 16; off <<= 1) {
                sT += __shfl_xor(sT, off);
                sM += __shfl_xor(sM, off);
            }
            float eT = __expf(sT), eM = __expf(sM);
            denT[q] += eT; denM[q] += eM;
            #pragma unroll
            for (int nt = 0; nt < 4; ++nt) {
                numT[q][nt] = fmaf(eT, hreg[q][nt], numT[q][nt]);
                numM[q][nt] = fmaf(eM, hreg[q][nt], numM[q][nt]);
            }
        }
    }

    #pragma unroll
    for (int q = 0; q < 4; ++q) {
        int row = rowbase + lhi*4 + q;
        float rT = 1.0f/denT[q], rM = 1.0f/denM[q];
        #pragma unroll
        for (int nt = 0; nt < 4; ++nt) {
            hT_out[row*HD + nt*16 + l16] = numT[q][nt]*rT;
            hM_out[row*HD + nt*16 + l16] = numM[q][nt]*rM;
        }
    }
}

// ---------------- Kernel B: both MLP heads + T10/M0 + X_out (unchanged, verified) ----------------
__global__ __launch_bounds__(256)
void mlp_out_kernel(const float* __restrict__ hT, const float* __restrict__ hM,
    const float* __restrict__ TW1, const float* __restrict__ Tb1,
    const float* __restrict__ TW2, const float* __restrict__ Tb2,
    const float* __restrict__ TW3, const float* __restrict__ Tb3,
    const float* __restrict__ MW1, const float* __restrict__ Mb1,
    const float* __restrict__ MW2, const float* __restrict__ Mb2,
    const float* __restrict__ MW3, const float* __restrict__ Mb3,
    const float* __restrict__ FA, const float* __restrict__ TR,
    float* __restrict__ out)
{
    __shared__ __align__(16) float xt[2][32][68];
    __shared__ __align__(16) float h1[32][204];
    __shared__ float part[8][32];
    __shared__ float rawv[2][32];
    __shared__ float Es[32], M0s[32];

    const int tid  = threadIdx.x;
    const int r    = tid & 31;
    const int g    = tid >> 5;
    const int row0 = blockIdx.x*32;

    for (int i = tid; i < 32*64; i += 256) {
        int rr = i >> 6, cc = i & 63;
        xt[0][rr][cc] = hT[(row0+rr)*64 + cc];
        xt[1][rr][cc] = hM[(row0+rr)*64 + cc];
    }
    __syncthreads();

    for (int brn = 0; brn < 2; ++brn) {
        const float* W1 = brn ? MW1 : TW1; const float* b1 = brn ? Mb1 : Tb1;
        const float* W2 = brn ? MW2 : TW2; const float* b2 = brn ? Mb2 : Tb2;
        const float* W3 = brn ? MW3 : TW3; const float* b3 = brn ? Mb3 : Tb3;

        #pragma unroll
        for (int jt = 0; jt < 5; ++jt) {
            float acc[5];
            int n0 = g + 40*jt;
            #pragma unroll
            for (int c = 0; c < 5; ++c) acc[c] = b1[n0 + 8*c];
            for (int k = 0; k < 64; k += 4) {
                float4 xv = *reinterpret_cast<const float4*>(&xt[brn][r][k]);
                #pragma unroll
                for (int c = 0; c < 5; ++c) {
                    float4 wv = *reinterpret_cast<const float4*>(&W1[(n0+8*c)*64 + k]);
                    acc[c] = fmaf(xv.x, wv.x, acc[c]);
                    acc[c] = fmaf(xv.y, wv.y, acc[c]);
                    acc[c] = fmaf(xv.z, wv.z, acc[c]);
                    acc[c] = fmaf(xv.w, wv.w, acc[c]);
                }
            }
            #pragma unroll
            for (int c = 0; c < 5; ++c) h1[r][n0 + 8*c] = felu(acc[c]);
        }
        __syncthreads();

        float contrib = 0.0f;
        #pragma unroll
        for (int jt = 0; jt < 5; ++jt) {
            float acc[5];
            int n0 = g + 40*jt;
            #pragma unroll
            for (int c = 0; c < 5; ++c) acc[c] = b2[n0 + 8*c];
            for (int k = 0; k < 200; k += 4) {
                float4 xv = *reinterpret_cast<const float4*>(&h1[r][k]);
                #pragma unroll
                for (int c = 0; c < 5; ++c) {
                    float4 wv = *reinterpret_cast<const float4*>(&W2[(n0+8*c)*200 + k]);
                    acc[c] = fmaf(xv.x, wv.x, acc[c]);
                    acc[c] = fmaf(xv.y, wv.y, acc[c]);
                    acc[c] = fmaf(xv.z, wv.z, acc[c]);
                    acc[c] = fmaf(xv.w, wv.w, acc[c]);
                }
            }
            #pragma unroll
            for (int c = 0; c < 5; ++c)
                contrib = fmaf(W3[n0 + 8*c], felu(acc[c]), contrib);
        }
        part[g][r] = contrib;
        __syncthreads();
        if (tid < 32) {
            float s = b3[0];
            #pragma unroll
            for (int q = 0; q < 8; ++q) s += part[q][tid];
            rawv[brn][tid] = s;
        }
        __syncthreads();
    }

    if (tid < 32) {
        int row = row0 + tid;
        float T10 = 0.1f + 4.9f*fsigmoid(rawv[0][tid]);
        float M0  = 10000.0f*fsigmoid(rawv[1][tid]);
        Es[tid]  = __expf(-TR[row]/T10);
        M0s[tid] = M0;
        out[(size_t)B_TOT*T_LEN + row]         = T10;
        out[(size_t)B_TOT*T_LEN + B_TOT + row] = M0;
    }
    __syncthreads();

    for (int i = tid; i < 32*T_LEN; i += 256) {
        int rr = i / T_LEN, t = i - rr*T_LEN;
        int row = row0 + rr;
        float fa = FA[row*T_LEN + t];
        float s = __sinf(fa), c = __cosf(fa);
        float Ev = Es[rr];
        out[row*T_LEN + t] = (1.0f - Ev)*s/(1.0f - c*Ev)*M0s[rr];
    }
}

extern "C" void kernel_launch(void* const* d_in, const int* in_sizes, int n_in,
                              void* d_out, int out_size, void* d_ws, size_t ws_size,
                              hipStream_t stream) {
    const float* Xin = (const float*)d_in[0];
    const float* FA  = (const float*)d_in[1];
    const float* TR  = (const float*)d_in[4];
    const float* Wih = (const float*)d_in[5];
    const float* Whh = (const float*)d_in[6];
    const float* bih = (const float*)d_in[7];
    const float* bhh = (const float*)d_in[8];
    const float* swT = (const float*)d_in[9];
    const float* swM = (const float*)d_in[10];
    const float* TW1 = (const float*)d_in[11]; const float* Tb1 = (const float*)d_in[12];
    const float* TW2 = (const float*)d_in[13]; const float* Tb2 = (const float*)d_in[14];
    const float* TW3 = (const float*)d_in[15]; const float* Tb3 = (const float*)d_in[16];
    const float* MW1 = (const float*)d_in[17]; const float* Mb1 = (const float*)d_in[18];
    const float* MW2 = (const float*)d_in[19]; const float* Mb2 = (const float*)d_in[20];
    const float* MW3 = (const float*)d_in[21]; const float* Mb3 = (const float*)d_in[22];
    float* out = (float*)d_out;

    float* hT = (float*)d_ws;
    float* hM = hT + (size_t)B_TOT*HD;

    gru_attn_mfma<<<B_TOT/64, 256, 0, stream>>>(Xin, FA, Wih, Whh, bih, bhh,
                                                swT, swM, hT, hM);
    mlp_out_kernel<<<B_TOT/32, 256, 0, stream>>>(hT, hM,
                                                 TW1, Tb1, TW2, Tb2, TW3, Tb3,
                                                 MW1, Mb1, MW2, Mb2, MW3, Mb3,
                                                 FA, TR, out);
}

// Round 3
// 547.155 us; speedup vs baseline: 4.0480x; 2.4095x over previous
//
#include <hip/hip_runtime.h>

#define B_TOT 65536
#define T_LEN 34
#define HD 64

typedef __attribute__((ext_vector_type(8))) short short8b;
typedef __attribute__((ext_vector_type(4))) short short4b;
typedef __attribute__((ext_vector_type(4))) float f32x4;

__device__ __forceinline__ float fsigmoid(float x){ return 1.0f/(1.0f+__expf(-x)); }
__device__ __forceinline__ float felu(float x){ return x>0.0f ? x : (__expf(x)-1.0f); }

__device__ __forceinline__ unsigned short f2bf_rne(float f){
    unsigned int u = __float_as_uint(f);
    u += 0x7FFFu + ((u >> 16) & 1u);
    return (unsigned short)(u >> 16);
}
__device__ __forceinline__ float bf2f(unsigned short h){
    return __uint_as_float(((unsigned int)h) << 16);
}
__device__ __forceinline__ unsigned short f2bf_fast(float f){
    unsigned int u = __float_as_uint(f);
    return (unsigned short)((u + 0x8000u) >> 16);
}
// split 8 f32 into hi (RNE bf16) + lo (RNE bf16 of residual): hi+lo ~= f32 exact
__device__ __forceinline__ void split8(const float4& a, const float4& b,
                                       short8b& hi, short8b& lo){
    float f[8] = {a.x,a.y,a.z,a.w,b.x,b.y,b.z,b.w};
    #pragma unroll
    for (int i = 0; i < 8; ++i){
        unsigned short h = f2bf_rne(f[i]);
        hi[i] = (short)h;
        lo[i] = (short)f2bf_rne(f[i] - bf2f(h));
    }
}

// ---------------- Kernel A: forward-fill + GRU (MFMA) + attention pooling ----------------
__global__ __launch_bounds__(256)
void gru_attn_mfma(const float* __restrict__ Xin, const float* __restrict__ FA,
                   const float* __restrict__ Wih, const float* __restrict__ Whh,
                   const float* __restrict__ bih, const float* __restrict__ bhh,
                   const float* __restrict__ swT, const float* __restrict__ swM,
                   float* __restrict__ hT_out, float* __restrict__ hM_out)
{
    __shared__ __align__(16) unsigned short WF[24*512];
    __shared__ __align__(16) unsigned short HL[4][1024];
    __shared__ __align__(8)  float XF[4][16][T_LEN][2];

    const int tid  = threadIdx.x;
    const int lane = tid & 63;
    const int wv   = tid >> 6;
    const int l16  = lane & 15;
    const int lhi  = lane >> 4;

    for (int f = wv; f < 24; f += 4) {
        int ks = f / 12, nt = f % 12;
        int u  = nt*16 + l16;
        int k0 = ks*32 + lhi*8;
        const float4 w0 = *reinterpret_cast<const float4*>(&Whh[u*64 + k0]);
        const float4 w1 = *reinterpret_cast<const float4*>(&Whh[u*64 + k0 + 4]);
        unsigned short* dst = &WF[f*512 + lane*8];
        dst[0]=f2bf_rne(w0.x); dst[1]=f2bf_rne(w0.y); dst[2]=f2bf_rne(w0.z); dst[3]=f2bf_rne(w0.w);
        dst[4]=f2bf_rne(w1.x); dst[5]=f2bf_rne(w1.y); dst[6]=f2bf_rne(w1.z); dst[7]=f2bf_rne(w1.w);
    }

    #pragma unroll
    for (int i = 0; i < 16; ++i) HL[wv][i*64 + lane] = 0;

    const int rowbase = blockIdx.x*64 + wv*16;

    for (int rr = 0; rr < 16; ++rr) {
        int row = rowbase + rr;
        float X = 0.0f, fa = 0.0f; int idx = -1;
        if (lane < T_LEN) {
            X  = Xin[row*T_LEN + lane];
            fa = FA [row*T_LEN + lane];
            if (X != 0.0f) idx = lane;
        }
        #pragma unroll
        for (int off = 1; off < 64; off <<= 1) {
            int v = __shfl_up(idx, off);
            if (lane >= off && v > idx) idx = v;
        }
        int gsrc = idx < 0 ? 0 : idx;
        float Xg = __shfl(X,  gsrc);
        float fg = __shfl(fa, gsrc);
        if (idx < 0) { Xg = 0.0f; fg = 0.0f; }
        if (lane < T_LEN) { XF[wv][rr][lane][0] = Xg; XF[wv][rr][lane][1] = fg; }
    }

    float wrx[4], wrf[4], wzx[4], wzf[4], wnx[4], wnf[4], bihn[4], wTc[4], wMc[4], biasD[12];
    #pragma unroll
    for (int nt = 0; nt < 4; ++nt) {
        int ul = nt*16 + l16;
        wrx[nt] = Wih[ ul*2     ]; wrf[nt] = Wih[ ul*2     +1];
        wzx[nt] = Wih[(64+ul)*2 ]; wzf[nt] = Wih[(64+ul)*2 +1];
        wnx[nt] = Wih[(128+ul)*2]; wnf[nt] = Wih[(128+ul)*2+1];
        bihn[nt] = bih[128+ul];
        wTc[nt] = swT[ul]; wMc[nt] = swM[ul];
    }
    #pragma unroll
    for (int nt = 0; nt < 12; ++nt) {
        int u = nt*16 + l16;
        biasD[nt] = (nt < 8) ? (bih[u] + bhh[u]) : bhh[u];
    }

    __syncthreads();

    const int swz   = (l16 & 7) << 3;
    const int aoff0 = l16*64 + ((     lhi*8) ^ swz);
    const int aoff1 = l16*64 + ((32 + lhi*8) ^ swz);

    float hreg[4][4] = {};
    float numT[4][4] = {}, numM[4][4] = {};
    float denT[4]    = {}, denM[4]    = {};

    const unsigned short* HLr = HL[wv];
    unsigned short*       HLw = HL[wv];

    for (int t = 0; t < T_LEN; ++t) {
        short8b a0 = *reinterpret_cast<const short8b*>(&HLr[aoff0]);
        short8b a1 = *reinterpret_cast<const short8b*>(&HLr[aoff1]);
        f32x4 acc[12];
        #pragma unroll
        for (int nt = 0; nt < 12; ++nt) {
            float b = biasD[nt];
            acc[nt] = (f32x4){b, b, b, b};
            acc[nt] = __builtin_amdgcn_mfma_f32_16x16x32_bf16(
                a0, *reinterpret_cast<const short8b*>(&WF[ nt     *512 + lane*8]), acc[nt], 0, 0, 0);
            acc[nt] = __builtin_amdgcn_mfma_f32_16x16x32_bf16(
                a1, *reinterpret_cast<const short8b*>(&WF[(12+nt)*512 + lane*8]), acc[nt], 0, 0, 0);
        }
        float vT[4], vM[4];
        #pragma unroll
        for (int q = 0; q < 4; ++q) {
            const int rloc = lhi*4 + q;
            const int rs   = (rloc & 7) << 3;
            float2 xf = *reinterpret_cast<const float2*>(&XF[wv][rloc][t][0]);
            float x = xf.x, fv = xf.y;
            float sT = 0.0f, sM = 0.0f;
            #pragma unroll
            for (int nt = 0; nt < 4; ++nt) {
                float Sr = acc[nt][q], Sz = acc[nt+4][q], Sn = acc[nt+8][q];
                float ur = fmaf(wrx[nt], x, fmaf(wrf[nt], fv, Sr));
                float uz = fmaf(wzx[nt], x, fmaf(wzf[nt], fv, Sz));
                float r  = 1.0f/(1.0f + __expf(-ur));
                float z  = 1.0f/(1.0f + __expf(-uz));
                float xn = fmaf(wnx[nt], x, fmaf(wnf[nt], fv, bihn[nt]));
                float v  = fmaf(r, Sn, xn);
                float n  = 1.0f - 2.0f/(1.0f + __expf(v + v));
                float hn = fmaf(z, hreg[q][nt] - n, n);
                hreg[q][nt] = hn;
                HLw[rloc*64 + ((((nt<<4) + l16)) ^ rs)] = f2bf_fast(hn);
                sT = fmaf(hn, wTc[nt], sT);
                sM = fmaf(hn, wMc[nt], sM);
            }
            vT[q] = sT; vM[q] = sM;
        }
        #pragma unroll
        for (int q = 0; q < 4; ++q) {
            float sT = vT[q], sM = vM[q];
            #pragma unroll
            for (int off = 1; off < 16; off <<= 1) {
                sT += __shfl_xor(sT, off);
                sM += __shfl_xor(sM, off);
            }
            float eT = __expf(sT), eM = __expf(sM);
            denT[q] += eT; denM[q] += eM;
            #pragma unroll
            for (int nt = 0; nt < 4; ++nt) {
                numT[q][nt] = fmaf(eT, hreg[q][nt], numT[q][nt]);
                numM[q][nt] = fmaf(eM, hreg[q][nt], numM[q][nt]);
            }
        }
    }

    #pragma unroll
    for (int q = 0; q < 4; ++q) {
        int row = rowbase + lhi*4 + q;
        float rT = 1.0f/denT[q], rM = 1.0f/denM[q];
        #pragma unroll
        for (int nt = 0; nt < 4; ++nt) {
            hT_out[row*HD + nt*16 + l16] = numT[q][nt]*rT;
            hM_out[row*HD + nt*16 + l16] = numM[q][nt]*rM;
        }
    }
}

// ---------------- Kernel B: MFMA MLP heads + T10/M0 + X_out ----------------
// 64 rows/block, 4 waves. Wave w owns N-tiles {w, w+4, w+8, (+12 for w0)}.
// Weights: hi/lo bf16 split streamed from global into B-fragments (no LDS).
// Activations: single bf16 RNE in LDS, XOR-granule swizzled (conflict-free b128).
__global__ __launch_bounds__(256)
void mlp_mfma(const float* __restrict__ hT, const float* __restrict__ hM,
    const float* __restrict__ TW1, const float* __restrict__ Tb1,
    const float* __restrict__ TW2, const float* __restrict__ Tb2,
    const float* __restrict__ TW3, const float* __restrict__ Tb3,
    const float* __restrict__ MW1, const float* __restrict__ Mb1,
    const float* __restrict__ MW2, const float* __restrict__ Mb2,
    const float* __restrict__ MW3, const float* __restrict__ Mb3,
    const float* __restrict__ FA, const float* __restrict__ TR,
    float* __restrict__ out)
{
    __shared__ __align__(16) unsigned short xh[2*64*64];   // 16 KB: [brn][row][k] swizzled
    __shared__ __align__(16) unsigned short h1s[64*256];   // 32 KB: [row][k] swizzled (k<224 used)
    __shared__ float praw[4][64];
    __shared__ float rawv[2][64];
    __shared__ float Es[64], M0s[64];

    const int tid  = threadIdx.x;
    const int lane = tid & 63;
    const int wv   = tid >> 6;
    const int l16  = lane & 15;
    const int lhi  = lane >> 4;
    const int row0 = blockIdx.x*64;

    // ---- phase 0: stage pooled features as bf16 (swizzled), zero H1 pad cols ----
    {
        int r  = tid >> 2;
        int k0 = (tid & 3) * 16;
        int rx = r & 7;
        const float* pT = &hT[(row0+r)*64 + k0];
        const float* pM = &hM[(row0+r)*64 + k0];
        #pragma unroll
        for (int j = 0; j < 4; ++j) {
            float4 vT = *reinterpret_cast<const float4*>(pT + 4*j);
            float4 vM = *reinterpret_cast<const float4*>(pM + 4*j);
            int kk = k0 + 4*j;
            int ad = r*64 + ((((kk>>3) ^ rx))<<3) + (kk&7);
            short4b sT = { (short)f2bf_rne(vT.x), (short)f2bf_rne(vT.y),
                           (short)f2bf_rne(vT.z), (short)f2bf_rne(vT.w) };
            short4b sM = { (short)f2bf_rne(vM.x), (short)f2bf_rne(vM.y),
                           (short)f2bf_rne(vM.z), (short)f2bf_rne(vM.w) };
            *reinterpret_cast<short4b*>(&xh[ad])        = sT;
            *reinterpret_cast<short4b*>(&xh[4096 + ad]) = sM;
        }
        for (int i = tid; i < 64*24; i += 256) {
            int rr = i / 24, kk = 200 + i % 24;
            h1s[rr*256 + ((((kk>>3) ^ (rr&7)))<<3) + (kk&7)] = 0;
        }
    }
    __syncthreads();

    for (int brn = 0; brn < 2; ++brn) {
        const float* W1 = brn ? MW1 : TW1; const float* b1 = brn ? Mb1 : Tb1;
        const float* W2 = brn ? MW2 : TW2; const float* b2 = brn ? Mb2 : Tb2;
        const float* W3 = brn ? MW3 : TW3; const float* b3 = brn ? Mb3 : Tb3;

        // ---- layer 1: [64,64] x W1^T -> ELU -> h1s ----
        for (int s = 0; s < 4; ++s) {
            int nt = wv + 4*s;
            if (nt > 12) break;
            int n  = nt*16 + l16;
            int nc = n < 200 ? n : 199;
            float bv = b1[nc];
            f32x4 acc[4];
            #pragma unroll
            for (int mt = 0; mt < 4; ++mt) acc[mt] = (f32x4){bv,bv,bv,bv};
            #pragma unroll
            for (int ks = 0; ks < 2; ++ks) {
                int k0 = ks*32 + lhi*8;
                const float* wp = &W1[nc*64 + k0];
                float4 w0 = *reinterpret_cast<const float4*>(wp);
                float4 w1 = *reinterpret_cast<const float4*>(wp + 4);
                short8b bh, bl;
                split8(w0, w1, bh, bl);
                #pragma unroll
                for (int mt = 0; mt < 4; ++mt) {
                    int rr = mt*16 + l16;
                    short8b a = *reinterpret_cast<const short8b*>(
                        &xh[brn*4096 + rr*64 + ((((k0>>3) ^ (rr&7)))<<3)]);
                    acc[mt] = __builtin_amdgcn_mfma_f32_16x16x32_bf16(a, bh, acc[mt], 0,0,0);
                    acc[mt] = __builtin_amdgcn_mfma_f32_16x16x32_bf16(a, bl, acc[mt], 0,0,0);
                }
            }
            if (n < 200) {
                #pragma unroll
                for (int mt = 0; mt < 4; ++mt) {
                    #pragma unroll
                    for (int q = 0; q < 4; ++q) {
                        int rr = mt*16 + lhi*4 + q;
                        h1s[rr*256 + ((((n>>3) ^ (rr&7)))<<3) + (n&7)] =
                            f2bf_rne(felu(acc[mt][q]));
                    }
                }
            }
        }
        __syncthreads();

        // ---- layer 2 (ELU) fused with layer-3 dot ----
        float p[4][4] = {};
        for (int s = 0; s < 4; ++s) {
            int nt = wv + 4*s;
            if (nt > 12) break;
            int n  = nt*16 + l16;
            int nc = n < 200 ? n : 199;
            float w3v = (n < 200) ? W3[nc] : 0.0f;
            float bv = b2[nc];
            f32x4 acc[4];
            #pragma unroll
            for (int mt = 0; mt < 4; ++mt) acc[mt] = (f32x4){bv,bv,bv,bv};
            for (int ks = 0; ks < 7; ++ks) {
                int k0 = ks*32 + lhi*8;
                short8b bh, bl;
                if (k0 + 8 <= 200) {
                    const float* wp = &W2[nc*200 + k0];
                    float4 w0 = *reinterpret_cast<const float4*>(wp);
                    float4 w1 = *reinterpret_cast<const float4*>(wp + 4);
                    split8(w0, w1, bh, bl);
                } else {
                    #pragma unroll
                    for (int i = 0; i < 8; ++i) { bh[i] = 0; bl[i] = 0; }
                }
                #pragma unroll
                for (int mt = 0; mt < 4; ++mt) {
                    int rr = mt*16 + l16;
                    short8b a = *reinterpret_cast<const short8b*>(
                        &h1s[rr*256 + ((((k0>>3) ^ (rr&7)))<<3)]);
                    acc[mt] = __builtin_amdgcn_mfma_f32_16x16x32_bf16(a, bh, acc[mt], 0,0,0);
                    acc[mt] = __builtin_amdgcn_mfma_f32_16x16x32_bf16(a, bl, acc[mt], 0,0,0);
                }
            }
            #pragma unroll
            for (int mt = 0; mt < 4; ++mt)
                #pragma unroll
                for (int q = 0; q < 4; ++q)
                    p[mt][q] = fmaf(w3v, felu(acc[mt][q]), p[mt][q]);
        }
        // reduce layer-3 partials over the 16 n-lanes
        #pragma unroll
        for (int off = 1; off < 16; off <<= 1) {
            #pragma unroll
            for (int mt = 0; mt < 4; ++mt)
                #pragma unroll
                for (int q = 0; q < 4; ++q)
                    p[mt][q] += __shfl_xor(p[mt][q], off);
        }
        if (l16 == 0) {
            #pragma unroll
            for (int mt = 0; mt < 4; ++mt)
                #pragma unroll
                for (int q = 0; q < 4; ++q)
                    praw[wv][mt*16 + lhi*4 + q] = p[mt][q];
        }
        __syncthreads();
        if (tid < 64)
            rawv[brn][tid] = b3[0] + praw[0][tid] + praw[1][tid] + praw[2][tid] + praw[3][tid];
        __syncthreads();
    }

    // ---- epilogue: T10/M0 + signal equation ----
    if (tid < 64) {
        int row = row0 + tid;
        float T10 = 0.1f + 4.9f*fsigmoid(rawv[0][tid]);
        float M0  = 10000.0f*fsigmoid(rawv[1][tid]);
        Es[tid]  = __expf(-TR[row]/T10);
        M0s[tid] = M0;
        out[(size_t)B_TOT*T_LEN + row]         = T10;
        out[(size_t)B_TOT*T_LEN + B_TOT + row] = M0;
    }
    __syncthreads();
    for (int i = tid; i < 64*T_LEN; i += 256) {
        int rr = i / T_LEN, t = i - rr*T_LEN;
        int row = row0 + rr;
        float fa = FA[row*T_LEN + t];
        float s = __sinf(fa), c = __cosf(fa);
        float Ev = Es[rr];
        out[row*T_LEN + t] = (1.0f - Ev)*s/(1.0f - c*Ev)*M0s[rr];
    }
}

extern "C" void kernel_launch(void* const* d_in, const int* in_sizes, int n_in,
                              void* d_out, int out_size, void* d_ws, size_t ws_size,
                              hipStream_t stream) {
    const float* Xin = (const float*)d_in[0];
    const float* FA  = (const float*)d_in[1];
    const float* TR  = (const float*)d_in[4];
    const float* Wih = (const float*)d_in[5];
    const float* Whh = (const float*)d_in[6];
    const float* bih = (const float*)d_in[7];
    const float* bhh = (const float*)d_in[8];
    const float* swT = (const float*)d_in[9];
    const float* swM = (const float*)d_in[10];
    const float* TW1 = (const float*)d_in[11]; const float* Tb1 = (const float*)d_in[12];
    const float* TW2 = (const float*)d_in[13]; const float* Tb2 = (const float*)d_in[14];
    const float* TW3 = (const float*)d_in[15]; const float* Tb3 = (const float*)d_in[16];
    const float* MW1 = (const float*)d_in[17]; const float* Mb1 = (const float*)d_in[18];
    const float* MW2 = (const float*)d_in[19]; const float* Mb2 = (const float*)d_in[20];
    const float* MW3 = (const float*)d_in[21]; const float* Mb3 = (const float*)d_in[22];
    float* out = (float*)d_out;

    float* hT = (float*)d_ws;
    float* hM = hT + (size_t)B_TOT*HD;

    gru_attn_mfma<<<B_TOT/64, 256, 0, stream>>>(Xin, FA, Wih, Whh, bih, bhh,
                                                swT, swM, hT, hM);
    mlp_mfma<<<B_TOT/64, 256, 0, stream>>>(hT, hM,
                                           TW1, Tb1, TW2, Tb2, TW3, Tb3,
                                           MW1, Mb1, MW2, Mb2, MW3, Mb3,
                                           FA, TR, out);
}